// Round 3
// baseline (132.472 us; speedup 1.0000x reference)
//
#include <hip/hip_runtime.h>
#include <hip/hip_bf16.h>
#include <stdint.h>

#define G_ 24
#define B_ 256
#define I_ 512
#define E_ 512
#define K_ (G_ * I_)   // 12288
#define SPLITK 5

typedef __hip_bfloat16 bf16;
typedef __bf16 bf16x8 __attribute__((ext_vector_type(8)));
typedef float f32x4 __attribute__((ext_vector_type(4)));

// ---------- input f32 -> bf16 ----------
__global__ void cvt_in_kernel(const float* __restrict__ in, bf16* __restrict__ out, int n4) {
  int idx = blockIdx.x * blockDim.x + threadIdx.x;
  if (idx >= n4) return;
  float4 v = reinterpret_cast<const float4*>(in)[idx];
  union { bf16 h[4]; uint2 u; } pk;
  pk.h[0] = __float2bfloat16(v.x);
  pk.h[1] = __float2bfloat16(v.y);
  pk.h[2] = __float2bfloat16(v.z);
  pk.h[3] = __float2bfloat16(v.w);
  reinterpret_cast<uint2*>(out)[idx] = pk.u;
}

// ---------- W[g][i][e] f32 -> Wt[g][e][i] bf16 ----------
__global__ void transpose_w_kernel(const float* __restrict__ W, bf16* __restrict__ Wt) {
  __shared__ float tile[32][33];
  const int g = blockIdx.z;
  const int i0 = blockIdx.x * 32;
  const int e0 = blockIdx.y * 32;
  const float* src = W + (size_t)g * (I_ * E_) + (size_t)(i0 + threadIdx.y) * E_ + e0 + threadIdx.x;
  #pragma unroll
  for (int r = 0; r < 32; r += 8)
    tile[threadIdx.y + r][threadIdx.x] = src[(size_t)r * E_];
  __syncthreads();
  bf16* dst = Wt + (size_t)g * (I_ * E_) + (size_t)(e0 + threadIdx.y) * I_ + i0 + threadIdx.x;
  #pragma unroll
  for (int r = 0; r < 32; r += 8)
    dst[(size_t)r * I_] = __float2bfloat16(tile[threadIdx.x][threadIdx.y + r]);
}

// ---------- out[b][h][e] = bias[e] ----------
__global__ void init_out_kernel(const float* __restrict__ bias, float* __restrict__ out, int n4) {
  int idx = blockIdx.x * blockDim.x + threadIdx.x;
  if (idx >= n4) return;
  int e4 = idx & 127;  // (E/4)=128 float4 per (b,h) row
  reinterpret_cast<float4*>(out)[idx] = reinterpret_cast<const float4*>(bias)[e4];
}

// ================= 8-phase 256x256 GEMM, split-K=5, atomic combine =================
// out[b,h,e] += sum_k A[b,k] * Wt[(k/512 - h)%24][e][k%512]
// BM=BN=256 (BM == full M), BK=64, 8 waves (2Mx4N), per-wave 128x64.
// 4 phases per K-tile; phase p computes one C-quadrant (16 MFMA) between barriers.
// Staging units match region liveness:
//   SA0 = A rows {0-63,128-191}   (read ph0, dead after ph0-end barrier)
//   SA1 = A rows {64-127,192-255} (read ph2, dead after ph2-end barrier)
//   SB0 = B e-bands {b*64+[0,32)} (read ph0, dead after ph0-end barrier)
//   SB1 = B e-bands {b*64+[32,64)}(read ph1, dead after ph1-end barrier)
// Stage plan during K-tile t (buf c = parity(t)):
//   ph0: SA1(t+1)->c^1   ph1: SB1(t+1)->c^1   ph2: SA0(t+2)->c   ph3: SB0(t+2)->c
// Counted waits: ph0-end vmcnt(6) (retires SA1(t),SB1(t));
//               ph3-end vmcnt(8) (retires SA0(t+1),SB0(t+1)). Never 0 mid-loop.
// XOR swizzle (both sides): dest LDS linear; source slot = chunk ^ (row&7);
// read addr slot = kslot ^ (row&7).

#define FENCE() asm volatile("" ::: "memory")
#define BAR()   __builtin_amdgcn_s_barrier()
#define LGKM0() do { asm volatile("s_waitcnt lgkmcnt(0)" ::: "memory"); \
                     __builtin_amdgcn_sched_barrier(0); } while (0)
#define VMW(N)  asm volatile("s_waitcnt vmcnt(" #N ")" ::: "memory")

__device__ __forceinline__ void gload16(const bf16* g, bf16* l) {
  __builtin_amdgcn_global_load_lds((const __attribute__((address_space(1))) void*)g,
                                   (__attribute__((address_space(3))) void*)l, 16, 0, 0);
}

__global__ __launch_bounds__(512, 2) void gemm256_kernel(
    const bf16* __restrict__ A,   // [256][12288]
    const bf16* __restrict__ Wt,  // [24][512(e)][512(i)]
    float* __restrict__ out) {    // [256][24][512], pre-init'd with bias

  __shared__ __align__(16) bf16 lds[2][2][256 * 64];  // [buf][A/B][rows*64] = 128 KB

  const int tid  = threadIdx.x;        // 0..511
  const int lane = tid & 63;
  const int wave = tid >> 6;           // 0..7
  const int wr   = wave >> 2;          // 0..1 -> 128 M-rows
  const int wc   = wave & 3;           // 0..3 -> 64 N-cols
  const int rsel = lane & 15;
  const int q    = lane >> 4;          // 0..3

  const int h     = blockIdx.z / SPLITK;
  const int split = blockIdx.z % SPLITK;
  const int n0    = blockIdx.x * 256;

  const int T0 = split * 38 + (split < 2 ? split : 2);
  const int NT = 38 + (split < 2 ? 1 : 0);

  f32x4 acc[8][4];
  #pragma unroll
  for (int i = 0; i < 8; ++i)
    #pragma unroll
    for (int j = 0; j < 4; ++j)
      acc[i][j] = (f32x4){0.f, 0.f, 0.f, 0.f};

  // ---- staging (2 global_load_lds per thread per unit) ----
  auto stageA = [&](int t, int half, int b) {
    const bf16* Ab = A + (size_t)t * 64;
    #pragma unroll
    for (int j = 0; j < 2; ++j) {
      int quarter = half + j * 2;                 // SA0:{0,2} SA1:{1,3}
      int row  = quarter * 64 + (tid >> 3);
      int slot = (tid & 7) ^ ((tid >> 3) & 7);
      gload16(Ab + (size_t)row * K_ + slot * 8,
              &lds[b][0][(size_t)(quarter * 512 + tid) * 8]);
    }
  };
  auto stageB = [&](int t, int half, int b) {
    int g = t >> 3, i0 = (t & 7) * 64;
    int gsrc = g - h; if (gsrc < 0) gsrc += G_;
    const bf16* Wb = Wt + (size_t)gsrc * (I_ * E_) + (size_t)n0 * I_ + i0;
    #pragma unroll
    for (int j = 0; j < 2; ++j) {
      int u    = j * 512 + tid;
      int band = u >> 8;
      int rowb = band * 64 + half * 32 + ((u >> 3) & 31);
      int slot = (u & 7) ^ ((u >> 3) & 7);
      gload16(Wb + (size_t)rowb * I_ + slot * 8,
              &lds[b][1][(size_t)(rowb * 8 + (u & 7)) * 8]);
    }
  };

  // ---- fragment reads ----
  bf16x8 af[8];   // A frags of current m-half: [mi(0..3)*2 + kk]
  bf16x8 b0f[4];  // B frags ni {0,1}: [ni*2 + kk]
  bf16x8 b1f[4];  // B frags ni {2,3}
  auto readA = [&](int mhalf, int b, bf16x8* dst) {
    const bf16* p = &lds[b][0][0];
    #pragma unroll
    for (int mi = 0; mi < 4; ++mi) {
      int r   = wr * 128 + (mhalf * 4 + mi) * 16 + rsel;
      int off = r * 64 + (q ^ (r & 7)) * 8;
      dst[mi * 2 + 0] = *(const bf16x8*)(p + off);
      dst[mi * 2 + 1] = *(const bf16x8*)(p + (off ^ 32));
    }
  };
  auto readB = [&](int nhalf, int b, bf16x8* dst) {
    const bf16* p = &lds[b][1][0];
    #pragma unroll
    for (int ni = 0; ni < 2; ++ni) {
      int r   = wc * 64 + (nhalf * 2 + ni) * 16 + rsel;
      int off = r * 64 + (q ^ (r & 7)) * 8;
      dst[ni * 2 + 0] = *(const bf16x8*)(p + off);
      dst[ni * 2 + 1] = *(const bf16x8*)(p + (off ^ 32));
    }
  };
  auto MMA = [&](int miB, int niB, bf16x8* a, bf16x8* bb) {
    #pragma unroll
    for (int kk = 0; kk < 2; ++kk)
      #pragma unroll
      for (int mi = 0; mi < 4; ++mi)
        #pragma unroll
        for (int ni = 0; ni < 2; ++ni)
          acc[miB + mi][niB + ni] = __builtin_amdgcn_mfma_f32_16x16x32_bf16(
              a[mi * 2 + kk], bb[ni * 2 + kk], acc[miB + mi][niB + ni], 0, 0, 0);
  };

#define KTILE(T, S1A, S1B, S2A, S2B, VMPH0, VMPH3) do {                         \
    /* ---- ph0: quadrant (m0,n0) ---- */                                       \
    if (S1A) stageA((T) + 1, 1, buf ^ 1);                                       \
    readA(0, buf, af); readB(0, buf, b0f);                                      \
    FENCE(); BAR(); LGKM0();                                                    \
    __builtin_amdgcn_s_setprio(1); MMA(0, 0, af, b0f); __builtin_amdgcn_s_setprio(0); \
    VMPH0; FENCE(); BAR();                                                      \
    /* ---- ph1: (m0,n1) ---- */                                                \
    if (S1B) stageB((T) + 1, 1, buf ^ 1);                                       \
    readB(1, buf, b1f);                                                         \
    FENCE(); BAR(); LGKM0();                                                    \
    __builtin_amdgcn_s_setprio(1); MMA(0, 2, af, b1f); __builtin_amdgcn_s_setprio(0); \
    FENCE(); BAR();                                                             \
    /* ---- ph2: (m1,n1) ---- */                                                \
    if (S2A) stageA((T) + 2, 0, buf);                                           \
    readA(1, buf, af);                                                          \
    FENCE(); BAR(); LGKM0();                                                    \
    __builtin_amdgcn_s_setprio(1); MMA(4, 2, af, b1f); __builtin_amdgcn_s_setprio(0); \
    FENCE(); BAR();                                                             \
    /* ---- ph3: (m1,n0) ---- */                                                \
    if (S2B) stageB((T) + 2, 0, buf);                                           \
    FENCE(); BAR();                                                             \
    __builtin_amdgcn_s_setprio(1); MMA(4, 0, af, b0f); __builtin_amdgcn_s_setprio(0); \
    VMPH3; FENCE(); BAR();                                                      \
    buf ^= 1;                                                                   \
  } while (0)

  // ---- prologue: SA0(T0),SB0(T0),SA1(T0),SB1(T0) -> buf0; SA0(T0+1),SB0(T0+1) -> buf1
  stageA(T0, 0, 0); stageB(T0, 0, 0);
  stageA(T0, 1, 0); stageB(T0, 1, 0);
  stageA(T0 + 1, 0, 1); stageB(T0 + 1, 0, 1);
  VMW(8);  // retire SA0(T0),SB0(T0); keep 8 loads in flight
  FENCE(); BAR();

  int buf = 0;
  for (int lt = 0; lt + 2 < NT; ++lt) {
    KTILE(T0 + lt, true, true, true, true, VMW(6), VMW(8));
  }
  // peeled K-tile NT-2: no t+2 stages; ph3-end needs vmcnt(4)
  KTILE(T0 + NT - 2, true, true, false, false, VMW(6), VMW(4));
  // peeled K-tile NT-1: no stages; ph0-end drains (vmcnt(0)); no ph3 wait
  KTILE(T0 + NT - 1, false, false, false, false, VMW(0), ((void)0));

#undef KTILE

  // ---- epilogue: atomic split-K combine. C/D: col=lane&15, row=(lane>>4)*4+reg
  #pragma unroll
  for (int mi = 0; mi < 8; ++mi) {
    #pragma unroll
    for (int ni = 0; ni < 4; ++ni) {
      int ecol  = n0 + wc * 64 + ni * 16 + (lane & 15);
      int brow0 = wr * 128 + mi * 16 + (lane >> 4) * 4;
      float* o = out + (size_t)brow0 * (G_ * E_) + (size_t)h * E_ + ecol;
      #pragma unroll
      for (int r = 0; r < 4; ++r)
        atomicAdd(o + (size_t)r * (G_ * E_), acc[mi][ni][r]);
    }
  }
}

extern "C" void kernel_launch(void* const* d_in, const int* in_sizes, int n_in,
                              void* d_out, int out_size, void* d_ws, size_t ws_size,
                              hipStream_t stream) {
  const float* in   = (const float*)d_in[0];
  const float* w    = (const float*)d_in[1];
  const float* bias = (const float*)d_in[2];
  float* out = (float*)d_out;

  bf16* A_bf = (bf16*)d_ws;                                   // 6.29 MB
  bf16* Wt   = (bf16*)((char*)d_ws + (size_t)B_ * K_ * 2);    // 12.58 MB

  const int n4in  = (B_ * K_) / 4;        // 786432
  const int n4out = (B_ * G_ * E_) / 4;   // 786432
  cvt_in_kernel<<<n4in / 256, 256, 0, stream>>>(in, A_bf, n4in);
  transpose_w_kernel<<<dim3(E_ / 32, I_ / 32, G_), dim3(32, 8), 0, stream>>>(w, Wt);
  init_out_kernel<<<n4out / 256, 256, 0, stream>>>(bias, out, n4out);
  gemm256_kernel<<<dim3(E_ / 256, 1, G_ * SPLITK), 512, 0, stream>>>(A_bf, Wt, out);
}

// Round 4
// 124.847 us; speedup vs baseline: 1.0611x; 1.0611x over previous
//
#include <hip/hip_runtime.h>
#include <hip/hip_bf16.h>
#include <stdint.h>

#define G_ 24
#define B_ 256
#define I_ 512
#define E_ 512
#define K_ (G_ * I_)   // 12288
#define SPLITK 4
#define NTILES 48      // K-tiles (BK=64) per split: 12288/64/4

typedef __hip_bfloat16 bf16;
typedef __bf16 bf16x8 __attribute__((ext_vector_type(8)));
typedef float f32x4 __attribute__((ext_vector_type(4)));

// ---------- input f32 -> bf16 ----------
__global__ void cvt_in_kernel(const float* __restrict__ in, bf16* __restrict__ out, int n4) {
  int idx = blockIdx.x * blockDim.x + threadIdx.x;
  if (idx >= n4) return;
  float4 v = reinterpret_cast<const float4*>(in)[idx];
  union { bf16 h[4]; uint2 u; } pk;
  pk.h[0] = __float2bfloat16(v.x);
  pk.h[1] = __float2bfloat16(v.y);
  pk.h[2] = __float2bfloat16(v.z);
  pk.h[3] = __float2bfloat16(v.w);
  reinterpret_cast<uint2*>(out)[idx] = pk.u;
}

// ---------- W[g][i][e] f32 -> Wt[g][e][i] bf16 ----------
__global__ void transpose_w_kernel(const float* __restrict__ W, bf16* __restrict__ Wt) {
  __shared__ float tile[32][33];
  const int g = blockIdx.z;
  const int i0 = blockIdx.x * 32;
  const int e0 = blockIdx.y * 32;
  const float* src = W + (size_t)g * (I_ * E_) + (size_t)(i0 + threadIdx.y) * E_ + e0 + threadIdx.x;
  #pragma unroll
  for (int r = 0; r < 32; r += 8)
    tile[threadIdx.y + r][threadIdx.x] = src[(size_t)r * E_];
  __syncthreads();
  bf16* dst = Wt + (size_t)g * (I_ * E_) + (size_t)(e0 + threadIdx.y) * I_ + i0 + threadIdx.x;
  #pragma unroll
  for (int r = 0; r < 32; r += 8)
    dst[(size_t)r * I_] = __float2bfloat16(tile[threadIdx.x][threadIdx.y + r]);
}

// ---------- out[b][h][e] = bias[e] ----------
__global__ void init_out_kernel(const float* __restrict__ bias, float* __restrict__ out, int n4) {
  int idx = blockIdx.x * blockDim.x + threadIdx.x;
  if (idx >= n4) return;
  int e4 = idx & 127;  // (E/4)=128 float4 per (b,h) row
  reinterpret_cast<float4*>(out)[idx] = reinterpret_cast<const float4*>(bias)[e4];
}

// ================= GEMM: BM=BN=128, BK=64, 4 waves of 64x64, splitK=4 =================
// out[b,h,e] += sum_k A[b,k] * Wt[(k/512 - h)%24][e][k%512]
// 2 WGs/CU resident (LDS 64 KB dbuf). Grid 768 (8x96), XCD-swizzled so each
// XCD's 96 WGs cover 12 consecutive (h,split) groups -> A 1.5MB + W 3MB per
// group fit XCD L2. 2-barrier counted-vmcnt loop (R2-proven), vmcnt(8) steady.
// XOR slot-swizzle both-sides: LDS dest linear, global source slot = c^(row&7),
// ds_read slot = kslot^(row&7). 128B LDS rows (proven conflict-free).
__global__ __launch_bounds__(256, 2) void gemm_kernel(
    const bf16* __restrict__ A,   // [256][12288]
    const bf16* __restrict__ Wt,  // [24][512(e)][512(i)]
    float* __restrict__ out) {    // [256][24][512], pre-init'd with bias

  __shared__ __align__(16) bf16 lds[2][2][128 * 64];  // [buf][A/B] 64 KB

  const int tid  = threadIdx.x;
  const int lane = tid & 63;
  const int wave = tid >> 6;
  const int wr   = wave >> 1;    // 0..1 -> 64 M-rows
  const int wc   = wave & 1;     // 0..1 -> 64 N-cols
  const int rsel = lane & 15;
  const int q    = lane >> 4;

  // XCD-aware swizzle: 768 WGs -> XCD x gets [x*96, (x+1)*96); decode n fastest.
  const int bid = blockIdx.x;
  const int swz = (bid & 7) * 96 + (bid >> 3);
  const int n0 = (swz & 3) * 128;
  const int m0 = ((swz >> 2) & 1) * 128;
  const int hs = swz >> 3;        // 0..95
  const int h  = hs >> 2;         // 0..23
  const int T0 = (hs & 3) * NTILES;

  f32x4 acc[4][4];
  #pragma unroll
  for (int i = 0; i < 4; ++i)
    #pragma unroll
    for (int j = 0; j < 4; ++j)
      acc[i][j] = (f32x4){0.f, 0.f, 0.f, 0.f};

  auto stage = [&](int t, int buf) {
    const int g  = t >> 3;          // 8 k-tiles per g
    const int i0 = (t & 7) * 64;
    int gsrc = g - h; if (gsrc < 0) gsrc += G_;
    const bf16* Abase = A  + (size_t)m0 * K_ + (size_t)t * 64;
    const bf16* Bbase = Wt + (size_t)gsrc * (I_ * E_) + (size_t)n0 * I_ + i0;
    #pragma unroll
    for (int j = 0; j < 4; ++j) {   // A: 1024 16B chunks
      int c    = j * 256 + tid;
      int row  = c >> 3;
      int slot = (c & 7) ^ (row & 7);
      __builtin_amdgcn_global_load_lds(
          (const __attribute__((address_space(1))) void*)(Abase + (size_t)row * K_ + slot * 8),
          (__attribute__((address_space(3))) void*)&lds[buf][0][(size_t)c * 8], 16, 0, 0);
    }
    #pragma unroll
    for (int j = 0; j < 4; ++j) {   // B: 1024 16B chunks
      int c    = j * 256 + tid;
      int row  = c >> 3;
      int slot = (c & 7) ^ (row & 7);
      __builtin_amdgcn_global_load_lds(
          (const __attribute__((address_space(1))) void*)(Bbase + (size_t)row * I_ + slot * 8),
          (__attribute__((address_space(3))) void*)&lds[buf][1][(size_t)c * 8], 16, 0, 0);
    }
  };

  stage(T0, 0);

  for (int lt = 0; lt < NTILES; ++lt) {
    const int cur = lt & 1;
    if (lt + 1 < NTILES) {
      stage(T0 + lt + 1, cur ^ 1);
      asm volatile("s_waitcnt vmcnt(8)" ::: "memory");  // retire stage(t); keep 8 in flight
    } else {
      asm volatile("s_waitcnt vmcnt(0)" ::: "memory");
    }
    __builtin_amdgcn_s_barrier();
    asm volatile("" ::: "memory");

    const bf16* Al = &lds[cur][0][0];
    const bf16* Bl = &lds[cur][1][0];
    #pragma unroll
    for (int kk = 0; kk < 2; ++kk) {          // two K=32 MFMA blocks per BK=64
      const int kslot = kk * 4 + q;
      bf16x8 af[4], bfr[4];
      #pragma unroll
      for (int mi = 0; mi < 4; ++mi) {
        int r = wr * 64 + mi * 16 + rsel;
        af[mi] = *(const bf16x8*)(Al + (size_t)r * 64 + (kslot ^ (r & 7)) * 8);
      }
      #pragma unroll
      for (int ni = 0; ni < 4; ++ni) {
        int r = wc * 64 + ni * 16 + rsel;
        bfr[ni] = *(const bf16x8*)(Bl + (size_t)r * 64 + (kslot ^ (r & 7)) * 8);
      }
      #pragma unroll
      for (int mi = 0; mi < 4; ++mi)
        #pragma unroll
        for (int ni = 0; ni < 4; ++ni)
          acc[mi][ni] = __builtin_amdgcn_mfma_f32_16x16x32_bf16(af[mi], bfr[ni], acc[mi][ni], 0, 0, 0);
    }

    asm volatile("s_waitcnt lgkmcnt(0)" ::: "memory");
    __builtin_amdgcn_s_barrier();
    asm volatile("" ::: "memory");
  }

  // epilogue: atomic split-K combine. C/D: col=lane&15, row=(lane>>4)*4+reg
  #pragma unroll
  for (int mi = 0; mi < 4; ++mi) {
    #pragma unroll
    for (int ni = 0; ni < 4; ++ni) {
      int ecol  = n0 + wc * 64 + ni * 16 + (lane & 15);
      int brow0 = m0 + wr * 64 + mi * 16 + (lane >> 4) * 4;
      float* o = out + (size_t)brow0 * (G_ * E_) + (size_t)h * E_ + ecol;
      #pragma unroll
      for (int r = 0; r < 4; ++r)
        atomicAdd(o + (size_t)r * (G_ * E_), acc[mi][ni][r]);
    }
  }
}

extern "C" void kernel_launch(void* const* d_in, const int* in_sizes, int n_in,
                              void* d_out, int out_size, void* d_ws, size_t ws_size,
                              hipStream_t stream) {
  const float* in   = (const float*)d_in[0];
  const float* w    = (const float*)d_in[1];
  const float* bias = (const float*)d_in[2];
  float* out = (float*)d_out;

  bf16* A_bf = (bf16*)d_ws;                                   // 6.29 MB
  bf16* Wt   = (bf16*)((char*)d_ws + (size_t)B_ * K_ * 2);    // 12.58 MB

  const int n4in  = (B_ * K_) / 4;        // 786432
  const int n4out = (B_ * G_ * E_) / 4;   // 786432
  cvt_in_kernel<<<n4in / 256, 256, 0, stream>>>(in, A_bf, n4in);
  transpose_w_kernel<<<dim3(E_ / 32, I_ / 32, G_), dim3(32, 8), 0, stream>>>(w, Wt);
  init_out_kernel<<<n4out / 256, 256, 0, stream>>>(bias, out, n4out);
  gemm_kernel<<<768, 256, 0, stream>>>(A_bf, Wt, out);
}